// Round 1
// baseline (99.995 us; speedup 1.0000x reference)
//
#include <hip/hip_runtime.h>

typedef float f4 __attribute__((ext_vector_type(4)));

constexpr int D  = 128;
constexpr int B  = 1024;
constexpr int S1 = 25;    // inner fanout (hop2 -> hop1)
constexpr int S2 = 10;    // outer fanout (hop1 -> hop0)

// ---------------------------------------------------------------------------
// Layer-0: producer/consumer pipelined kernel.
//   grid = 256 blocks (1 per CU), 256 threads.
//   704 tiles of 16 rows: tiles [0,640) -> nh1 (neigh fanout 25),
//                         tiles [640,704) -> nh0 (neigh fanout 10).
//   Block b owns tiles {b, b+256, b+512} (2 or 3 tiles).
//   Waves 0-1 (t<128): gather tile i+1 into LDS buf[(i+1)&1].
//   Waves 2-3 (t>=128): matmul tile i from LDS buf[i&1], store with relu.
//   One __syncthreads per tile; double buffer makes it race-free.
// ---------------------------------------------------------------------------
constexpr int TR    = 16;              // rows per tile
constexpr int NT1   = (B * S2) / TR;   // 640 nh1 tiles
constexpr int NT    = NT1 + B / TR;    // 704 total
constexpr int GRID0 = 256;

template <int NB>
__device__ __forceinline__ void gather_tile(
    const float* __restrict__ feat, const int* __restrict__ self_idx,
    const int* __restrict__ neigh_idx, int base, int t,
    float (*lds_h)[D], float (*lds_m)[D])
{
    // t in [0,128): l = 16B chunk within row, rg = row group; each thread
    // handles rows {rg, rg+4, rg+8, rg+12} sequentially (bounded VGPRs,
    // ~26 loads in flight per row is ample MLP at 1 block/CU).
    const int l  = t & 31;
    const int rg = t >> 5;   // [0,4)
    #pragma unroll 1
    for (int rr = 0; rr < 4; ++rr) {
        const int r = rg + rr * 4;
        const int* __restrict__ idx = neigh_idx + (long)(base + r) * NB;
        f4 acc = {0.f, 0.f, 0.f, 0.f};
        #pragma unroll
        for (int s = 0; s < NB; ++s)
            acc += *((const f4*)(feat + (long)idx[s] * D) + l);
        const f4 sv = *((const f4*)(feat + (long)self_idx[base + r] * D) + l);
        *(f4*)(&lds_m[r][l * 4]) = acc * (1.f / NB);
        *(f4*)(&lds_h[r][l * 4]) = sv;
    }
}

__global__ __launch_bounds__(256, 3) void layer0_pipe_kernel(
    const float* __restrict__ feat,
    const int* __restrict__ s0, const int* __restrict__ s1,
    const int* __restrict__ s2,
    const float* __restrict__ Ws0, const float* __restrict__ Wn0,
    float* __restrict__ nh1, float* __restrict__ nh0)
{
    __shared__ float lds_h[2][TR][D];
    __shared__ float lds_m[2][TR][D];

    const int b = blockIdx.x;
    const int t = threadIdx.x;
    const int ntl = (b + 2 * GRID0 < NT) ? 3 : 2;

    // prologue: gather first tile into buffer 0 (consumers wait at barrier)
    if (t < 128) {
        if (b < NT1) gather_tile<S1>(feat, s1, s2, b * TR, t, lds_h[0], lds_m[0]);
        else         gather_tile<S2>(feat, s0, s1, (b - NT1) * TR, t, lds_h[0], lds_m[0]);
    }
    __syncthreads();

    for (int i = 0; i < ntl; ++i) {
        if (t < 128) {
            // producers: prefetch next tile into the other buffer
            if (i + 1 < ntl) {
                const int tt = b + (i + 1) * GRID0;
                const int bf = (i + 1) & 1;
                if (tt < NT1)
                    gather_tile<S1>(feat, s1, s2, tt * TR, t, lds_h[bf], lds_m[bf]);
                else
                    gather_tile<S2>(feat, s0, s1, (tt - NT1) * TR, t, lds_h[bf], lds_m[bf]);
            }
        } else {
            // consumers: matmul current tile. d = column, 16 rows per thread.
            const int tt   = b + i * GRID0;
            float* __restrict__ out = (tt < NT1) ? nh1 : nh0;
            const int base = (tt < NT1) ? tt * TR : (tt - NT1) * TR;
            const int d    = t - 128;
            const int bf   = i & 1;

            float acc[TR];
            #pragma unroll
            for (int r = 0; r < TR; ++r) acc[r] = 0.f;

            #pragma unroll 4
            for (int k4 = 0; k4 < D / 4; ++k4) {
                const int k = k4 * 4;
                const float ws0 = Ws0[(k + 0) * D + d];
                const float ws1 = Ws0[(k + 1) * D + d];
                const float ws2 = Ws0[(k + 2) * D + d];
                const float ws3 = Ws0[(k + 3) * D + d];
                const float wn0 = Wn0[(k + 0) * D + d];
                const float wn1 = Wn0[(k + 1) * D + d];
                const float wn2 = Wn0[(k + 2) * D + d];
                const float wn3 = Wn0[(k + 3) * D + d];
                #pragma unroll
                for (int r = 0; r < TR; ++r) {
                    const f4 hv = *(const f4*)(&lds_h[bf][r][k]);
                    const f4 mv = *(const f4*)(&lds_m[bf][r][k]);
                    acc[r] += hv.x * ws0 + hv.y * ws1 + hv.z * ws2 + hv.w * ws3
                            + mv.x * wn0 + mv.y * wn1 + mv.z * wn2 + mv.w * wn3;
                }
            }

            #pragma unroll
            for (int r = 0; r < TR; ++r)
                out[(long)(base + r) * D + d] = fmaxf(acc[r], 0.f);
        }
        __syncthreads();
    }
}

// ---------------------------------------------------------------------------
// Layer 1: self = nh0 rows direct; mean over S2 contiguous nh1 rows; identity.
// nh1/nh0 are L2-hot from layer 0; this kernel is small (~5 µs incl. launch).
// ---------------------------------------------------------------------------
constexpr int RPB_L = 4;
__global__ __launch_bounds__(128) void layer1_kernel(
    const float* __restrict__ nh0, const float* __restrict__ nh1,
    const float* __restrict__ Ws1, const float* __restrict__ Wn1,
    float* __restrict__ out)
{
    __shared__ float lds_h[RPB_L][D];
    __shared__ float lds_m[RPB_L][D];
    const int tid  = threadIdx.x;
    const int base = blockIdx.x * RPB_L;

    #pragma unroll
    for (int r = 0; r < RPB_L; ++r) {
        const int row = base + r;
        lds_h[r][tid] = nh0[(long)row * D + tid];
        float s = 0.f;
        #pragma unroll
        for (int n = 0; n < S2; ++n)
            s += nh1[((long)row * S2 + n) * D + tid];
        lds_m[r][tid] = s * (1.f / S2);
    }
    __syncthreads();

    const int d = tid;
    float acc[RPB_L];
    #pragma unroll
    for (int r = 0; r < RPB_L; ++r) acc[r] = 0.f;

    #pragma unroll 4
    for (int k4 = 0; k4 < D / 4; ++k4) {
        const int k = k4 * 4;
        const float ws0 = Ws1[(k + 0) * D + d];
        const float ws1 = Ws1[(k + 1) * D + d];
        const float ws2 = Ws1[(k + 2) * D + d];
        const float ws3 = Ws1[(k + 3) * D + d];
        const float wn0 = Wn1[(k + 0) * D + d];
        const float wn1 = Wn1[(k + 1) * D + d];
        const float wn2 = Wn1[(k + 2) * D + d];
        const float wn3 = Wn1[(k + 3) * D + d];
        #pragma unroll
        for (int r = 0; r < RPB_L; ++r) {
            const f4 hv = *(const f4*)(&lds_h[r][k]);
            const f4 mv = *(const f4*)(&lds_m[r][k]);
            acc[r] += hv.x * ws0 + hv.y * ws1 + hv.z * ws2 + hv.w * ws3
                    + mv.x * wn0 + mv.y * wn1 + mv.z * wn2 + mv.w * wn3;
        }
    }

    #pragma unroll
    for (int r = 0; r < RPB_L; ++r)
        out[(long)(base + r) * D + d] = acc[r];
}

extern "C" void kernel_launch(void* const* d_in, const int* in_sizes, int n_in,
                              void* d_out, int out_size, void* d_ws, size_t ws_size,
                              hipStream_t stream)
{
    const float* feat = (const float*)d_in[0];
    const float* Ws0  = (const float*)d_in[1];
    const float* Wn0  = (const float*)d_in[2];
    const float* Ws1  = (const float*)d_in[3];
    const float* Wn1  = (const float*)d_in[4];
    const int*   s0   = (const int*)d_in[5];
    const int*   s1   = (const int*)d_in[6];
    const int*   s2   = (const int*)d_in[7];
    float* out = (float*)d_out;

    float* nh1 = (float*)d_ws;                   // [B*S2, D]
    float* nh0 = nh1 + (size_t)(B * S2) * D;     // [B, D]

    layer0_pipe_kernel<<<GRID0, 256, 0, stream>>>(feat, s0, s1, s2, Ws0, Wn0, nh1, nh0);
    layer1_kernel<<<B / RPB_L, 128, 0, stream>>>(nh0, nh1, Ws1, Wn1, out);
}